// Round 6
// baseline (155.462 us; speedup 1.0000x reference)
//
#include <hip/hip_runtime.h>
#include <math.h>

#define HH   50
#define NNEG 10
#define EE   128
#define EPSF 1e-6f

// ONE WAVE per batch element (4 independent waves per 256-thread block).
// Wave = 4 groups x 16 lanes; a group owns one embedding row per iteration,
// each lane holding 8 contiguous floats (2x float4). No LDS, no __syncthreads:
// in-group 4-step butterflies + one cross-group (xor 16,32) butterfly do all
// reductions in-register. Softmax max-subtraction skipped (s2h <= 0.031,
// exp safe; validated absmax=0 in rounds 3-5).
__global__ __launch_bounds__(256, 8) void htne_kernel(
    const int*   __restrict__ s_nodes,   // [B,1]
    const int*   __restrict__ t_nodes,   // [B,1]
    const float* __restrict__ t_times,   // [B,1]
    const int*   __restrict__ h_nodes,   // [B,H]
    const float* __restrict__ h_times,   // [B,H]
    const float* __restrict__ h_mask,    // [B,H]
    const int*   __restrict__ n_nodes,   // [B,N]
    const float* __restrict__ emb,       // [V,E]
    const float* __restrict__ delta_w,   // [V,1]
    float*       __restrict__ out,       // [B]
    int B)
{
    const int tid  = threadIdx.x;
    const int wid  = tid >> 6;
    const int lane = tid & 63;
    const int g    = lane >> 4;          // group 0..3
    const int sub  = lane & 15;          // lane-in-group
    const int b    = blockIdx.x * 4 + wid;
    if (b >= B) return;

    const int   sidx  = s_nodes[b];
    const int   tidx  = t_nodes[b];
    const float tt    = t_times[b];
    const float delta = delta_w[sidx];

    // per-lane 8-elem slice of src/tar rows (same addr across groups -> broadcast)
    float sva[8], tva[8];
    {
        float4 a0 = *(const float4*)(emb + (size_t)sidx * EE + sub * 8);
        float4 a1 = *(const float4*)(emb + (size_t)sidx * EE + sub * 8 + 4);
        float4 b0 = *(const float4*)(emb + (size_t)tidx * EE + sub * 8);
        float4 b1 = *(const float4*)(emb + (size_t)tidx * EE + sub * 8 + 4);
        sva[0]=a0.x; sva[1]=a0.y; sva[2]=a0.z; sva[3]=a0.w;
        sva[4]=a1.x; sva[5]=a1.y; sva[6]=a1.z; sva[7]=a1.w;
        tva[0]=b0.x; tva[1]=b0.y; tva[2]=b0.z; tva[3]=b0.w;
        tva[4]=b1.x; tva[5]=b1.y; tva[6]=b1.z; tva[7]=b1.w;
    }

    float SE = 0.f, UW = 0.f, UH = 0.f, UP = 0.f, S2T = 0.f;
    float hb[8] = {0.f,0.f,0.f,0.f,0.f,0.f,0.f,0.f};

    // ---- Phase 1: 50 his rows + s2t over 13 iterations (4 rows/iter) ----
    #pragma unroll
    for (int it = 0; it < 13; ++it) {
        const int t = it * 4 + g;
        if (t < HH) {
            const int idx = h_nodes[b * HH + t];
            const float* hrow = emb + (size_t)idx * EE + sub * 8;
            float4 h0 = *(const float4*)(hrow);
            float4 h1 = *(const float4*)(hrow + 4);
            const float htm = h_times[b * HH + t];   // group-uniform broadcast
            const float hmk = h_mask[b * HH + t];
            float hv[8] = {h0.x,h0.y,h0.z,h0.w,h1.x,h1.y,h1.z,h1.w};
            float a = 0.f, c = 0.f, q = 0.f;
            #pragma unroll
            for (int k = 0; k < 8; ++k) {
                float d1 = hv[k] - sva[k];
                float d2 = hv[k] - tva[k];
                a = fmaf(d1, d1, a);       // ||his-src||^2
                c = fmaf(d2, d2, c);       // ||his-tar||^2
                q = fmaf(hv[k], hv[k], q); // ||his||^2
            }
            #pragma unroll
            for (int off = 1; off <= 8; off <<= 1) {
                a += __shfl_xor(a, off);
                c += __shfl_xor(c, off);
                q += __shfl_xor(q, off);
            }
            const float e1 = __expf(-a);
            const float u  = e1 * __expf(delta * fabsf(tt - htm)) * hmk;
            SE += e1; UW += u; UH += u * q; UP += u * c;
            #pragma unroll
            for (int k = 0; k < 8; ++k) hb[k] = fmaf(u, hv[k], hb[k]);
        } else if (t == HH) {              // it==12, g==2: ||src-tar||^2
            float a = 0.f;
            #pragma unroll
            for (int k = 0; k < 8; ++k) {
                float d = sva[k] - tva[k];
                a = fmaf(d, d, a);
            }
            #pragma unroll
            for (int off = 1; off <= 8; off <<= 1) a += __shfl_xor(a, off);
            S2T = a;                       // groups != 2 contribute 0
        }
    }

    // ---- cross-group butterfly: totals + full uhbar slice in every lane ----
    #pragma unroll
    for (int off = 16; off <= 32; off <<= 1) {
        SE  += __shfl_xor(SE,  off);
        UW  += __shfl_xor(UW,  off);
        UH  += __shfl_xor(UH,  off);
        UP  += __shfl_xor(UP,  off);
        S2T += __shfl_xor(S2T, off);
        #pragma unroll
        for (int k = 0; k < 8; ++k) hb[k] += __shfl_xor(hb[k], off);
    }

    // ---- Phase 2: 10 neg rows (4/iter), loaded once, fully in-wave ----
    float NL = 0.f;   // per-lane partial of sum_n log(sigmoid(-nl)+eps)
    #pragma unroll
    for (int it = 0; it < 3; ++it) {
        const int n = it * 4 + g;
        if (n < NNEG) {
            const int idx = n_nodes[b * NNEG + n];
            const float* nrow = emb + (size_t)idx * EE + sub * 8;
            float4 n0 = *(const float4*)(nrow);
            float4 n1 = *(const float4*)(nrow + 4);
            float nv[8] = {n0.x,n0.y,n0.z,n0.w,n1.x,n1.y,n1.z,n1.w};
            float a = 0.f, q = 0.f, d = 0.f;
            #pragma unroll
            for (int k = 0; k < 8; ++k) {
                float d1 = nv[k] - sva[k];
                a = fmaf(d1, d1, a);        // ||src-neg||^2
                q = fmaf(nv[k], nv[k], q);  // ||neg||^2
                d = fmaf(hb[k], nv[k], d);  // uhbar . neg
            }
            #pragma unroll
            for (int off = 1; off <= 8; off <<= 1) {
                a += __shfl_xor(a, off);
                q += __shfl_xor(q, off);
                d += __shfl_xor(d, off);
            }
            const float nl = -a - (UH + q * UW - 2.f * d) / SE;   // n_lambda
            NL += __logf(1.f / (1.f + __expf(nl)) + EPSF) * (1.f / 16.f);
            // (all 16 lanes of the group add the same value; /16 fixes it and
            //  keeps the final reduce a plain butterfly)
        }
    }
    // total neg_loss: sum across ALL lanes (each group's 16 lanes hold its
    // negs' terms /16). Full 6-step... 16-lane part first, then cross-group.
    #pragma unroll
    for (int off = 1; off <= 32; off <<= 1) NL += __shfl_xor(NL, off);

    // ---- epilogue ----
    if (lane == 0) {
        const float pl  = -S2T - UP / SE;                          // p_lambda
        const float pos = -__logf(1.f / (1.f + __expf(-pl)) + EPSF);
        out[b] = pos - NL;
    }
}

extern "C" void kernel_launch(void* const* d_in, const int* in_sizes, int n_in,
                              void* d_out, int out_size, void* d_ws, size_t ws_size,
                              hipStream_t stream) {
    const int*   s_nodes = (const int*)  d_in[0];
    const int*   t_nodes = (const int*)  d_in[1];
    const float* t_times = (const float*)d_in[2];
    const int*   h_nodes = (const int*)  d_in[3];
    const float* h_times = (const float*)d_in[4];
    const float* h_mask  = (const float*)d_in[5];
    const int*   n_nodes = (const int*)  d_in[6];
    const float* emb     = (const float*)d_in[7];
    const float* delta_w = (const float*)d_in[8];
    float*       out     = (float*)d_out;

    const int Bn = in_sizes[0];                  // 4096
    const int grid = (Bn + 3) / 4;               // 4 waves (batch elems) / block
    htne_kernel<<<grid, 256, 0, stream>>>(s_nodes, t_nodes, t_times, h_nodes,
                                          h_times, h_mask, n_nodes, emb, delta_w,
                                          out, Bn);
}

// Round 7
// 31.720 us; speedup vs baseline: 4.9011x; 4.9011x over previous
//
#include <hip/hip_runtime.h>
#include <math.h>

#define HH   50
#define NNEG 10
#define EE   128
#define EPSF 1e-6f

// One block (4 waves) per batch element; 16 groups x 16 lanes, lane holds 8
// contiguous floats (2x float4) of a row. Single load pass with FORCED
// prefetch: all 4 task-rows per group (8x dwordx4) are issued back-to-back
// into registers before any compute, so gather latency overlaps across tasks
// (MLP=8/wave) instead of serializing. launch_bounds(256,4) raises the VGPR
// cap to 128 so the prefetch block fits WITHOUT spilling (round 6 lesson:
// WRITE_SIZE is the spill tripwire — must stay ~0.1 MB).
// Tasks: t=g+16*it; t<50 his row, t==50 ||src-tar||^2, 51..60 neg rows
// (neg row = the it==3 prefetch, reused in phase 2 from registers).
// Softmax max-subtraction skipped: s2h <= 128*(2/128)^2 ~= 0.031, exp safe
// (validated absmax=0 in rounds 3-6).
__global__ __launch_bounds__(256, 4) void htne_kernel(
    const int*   __restrict__ s_nodes,   // [B,1]
    const int*   __restrict__ t_nodes,   // [B,1]
    const float* __restrict__ t_times,   // [B,1]
    const int*   __restrict__ h_nodes,   // [B,H]
    const float* __restrict__ h_times,   // [B,H]
    const float* __restrict__ h_mask,    // [B,H]
    const int*   __restrict__ n_nodes,   // [B,N]
    const float* __restrict__ emb,       // [V,E]
    const float* __restrict__ delta_w,   // [V,1]
    float*       __restrict__ out)       // [B]
{
    __shared__ float s_part[4][EE];      // per-wave unnormalized hbar partials
    __shared__ float s_scw[4][4];        // per-wave SE, UW, UH, UP
    __shared__ float s_s2t;
    __shared__ float s_nl[NNEG];

    const int b    = blockIdx.x;
    const int tid  = threadIdx.x;
    const int wid  = tid >> 6;
    const int lane = tid & 63;
    const int g    = tid >> 4;           // group 0..15
    const int sub  = tid & 15;           // lane-in-group

    const int   sidx  = s_nodes[b];
    const int   tidx  = t_nodes[b];
    const float tt    = t_times[b];
    const float delta = delta_w[sidx];

    // ---- per-task metadata (breaks idx->row dependence) ----
    int   ridx[4];
    float htm[4], hmk[4];
    #pragma unroll
    for (int it = 0; it < 4; ++it) {
        const int t = g + it * 16;
        if (t < HH) {
            ridx[it] = h_nodes[b * HH + t];
            htm[it]  = h_times[b * HH + t];
            hmk[it]  = h_mask[b * HH + t];
        } else if (t > HH && t <= HH + NNEG) {
            ridx[it] = n_nodes[b * NNEG + (t - HH - 1)];
            htm[it] = 0.f; hmk[it] = 0.f;
        } else {                         // t==50 (s2t) or idle: load src row (L1-hot)
            ridx[it] = sidx;
            htm[it] = 0.f; hmk[it] = 0.f;
        }
    }

    // ---- forced prefetch: 8 gather loads + 4 broadcast loads, all in flight ----
    float4 r0[4], r1[4];
    #pragma unroll
    for (int it = 0; it < 4; ++it) {
        const float* p = emb + (size_t)ridx[it] * EE + sub * 8;
        r0[it] = *(const float4*)(p);
        r1[it] = *(const float4*)(p + 4);
    }
    float4 sa0 = *(const float4*)(emb + (size_t)sidx * EE + sub * 8);
    float4 sa1 = *(const float4*)(emb + (size_t)sidx * EE + sub * 8 + 4);
    float4 ta0 = *(const float4*)(emb + (size_t)tidx * EE + sub * 8);
    float4 ta1 = *(const float4*)(emb + (size_t)tidx * EE + sub * 8 + 4);
    float sva[8] = {sa0.x,sa0.y,sa0.z,sa0.w,sa1.x,sa1.y,sa1.z,sa1.w};
    float tva[8] = {ta0.x,ta0.y,ta0.z,ta0.w,ta1.x,ta1.y,ta1.z,ta1.w};

    float SE = 0.f, UW = 0.f, UH = 0.f, UP = 0.f;
    float hb[8] = {0.f,0.f,0.f,0.f,0.f,0.f,0.f,0.f};
    float nA = 0.f, nQ = 0.f;            // neg-row reduced stats (groups 3..12)

    // ---- compute pass over the 4 prefetched tasks ----
    #pragma unroll
    for (int it = 0; it < 4; ++it) {
        const int t = g + it * 16;
        const float hv[8] = {r0[it].x,r0[it].y,r0[it].z,r0[it].w,
                             r1[it].x,r1[it].y,r1[it].z,r1[it].w};
        if (t < HH) {                    // ---- his row ----
            float a = 0.f, c = 0.f, q = 0.f;
            #pragma unroll
            for (int k = 0; k < 8; ++k) {
                float d1 = hv[k] - sva[k];
                float d2 = hv[k] - tva[k];
                a = fmaf(d1, d1, a);       // ||his-src||^2
                c = fmaf(d2, d2, c);       // ||his-tar||^2
                q = fmaf(hv[k], hv[k], q); // ||his||^2
            }
            #pragma unroll
            for (int off = 1; off <= 8; off <<= 1) {
                a += __shfl_xor(a, off);
                c += __shfl_xor(c, off);
                q += __shfl_xor(q, off);
            }
            const float e1 = __expf(-a);
            const float u  = e1 * __expf(delta * fabsf(tt - htm[it])) * hmk[it];
            SE += e1; UW += u; UH += u * q; UP += u * c;
            #pragma unroll
            for (int k = 0; k < 8; ++k) hb[k] = fmaf(u, hv[k], hb[k]);
        } else if (it == 3) {
            if (t == HH) {               // ---- ||src-tar||^2 (group 2) ----
                float a = 0.f;
                #pragma unroll
                for (int k = 0; k < 8; ++k) {
                    float d = sva[k] - tva[k];
                    a = fmaf(d, d, a);
                }
                #pragma unroll
                for (int off = 1; off <= 8; off <<= 1) a += __shfl_xor(a, off);
                if (sub == 0) s_s2t = a;
            } else if (t <= HH + NNEG) { // ---- neg row stats (groups 3..12) ----
                float a = 0.f, q = 0.f;
                #pragma unroll
                for (int k = 0; k < 8; ++k) {
                    float d1 = hv[k] - sva[k];
                    a = fmaf(d1, d1, a);   // ||src-neg||^2
                    q = fmaf(hv[k], hv[k], q);
                }
                #pragma unroll
                for (int off = 1; off <= 8; off <<= 1) {
                    a += __shfl_xor(a, off);
                    q += __shfl_xor(q, off);
                }
                nA = a; nQ = q;
            }
        }
    }

    // ---- cross-group butterfly (xor 16, 32): wave-level partials ----
    #pragma unroll
    for (int off = 16; off <= 32; off <<= 1) {
        SE += __shfl_xor(SE, off);
        UW += __shfl_xor(UW, off);
        UH += __shfl_xor(UH, off);
        UP += __shfl_xor(UP, off);
        #pragma unroll
        for (int k = 0; k < 8; ++k) hb[k] += __shfl_xor(hb[k], off);
    }
    if (lane < 16) {
        *(float4*)(&s_part[wid][sub * 8])     = make_float4(hb[0],hb[1],hb[2],hb[3]);
        *(float4*)(&s_part[wid][sub * 8 + 4]) = make_float4(hb[4],hb[5],hb[6],hb[7]);
    }
    if (lane == 0) {
        s_scw[wid][0] = SE; s_scw[wid][1] = UW;
        s_scw[wid][2] = UH; s_scw[wid][3] = UP;
    }
    __syncthreads();

    const float SEt = s_scw[0][0] + s_scw[1][0] + s_scw[2][0] + s_scw[3][0];
    const float UWt = s_scw[0][1] + s_scw[1][1] + s_scw[2][1] + s_scw[3][1];
    const float UHt = s_scw[0][2] + s_scw[1][2] + s_scw[2][2] + s_scw[3][2];

    // ---- finish negs from the it==3 prefetch registers (no second gather) ----
    if (g >= 3 && g <= 12) {
        const float nv[8] = {r0[3].x,r0[3].y,r0[3].z,r0[3].w,
                             r1[3].x,r1[3].y,r1[3].z,r1[3].w};
        float d = 0.f;
        #pragma unroll
        for (int k = 0; k < 8; ++k) {
            float hbs = s_part[0][sub*8+k] + s_part[1][sub*8+k]
                      + s_part[2][sub*8+k] + s_part[3][sub*8+k];
            d = fmaf(hbs, nv[k], d);
        }
        #pragma unroll
        for (int off = 1; off <= 8; off <<= 1) d += __shfl_xor(d, off);
        if (sub == 0) {
            float nl = -nA - (UHt + nQ * UWt - 2.f * d) / SEt;   // n_lambda
            s_nl[g - 3] = __logf(1.f / (1.f + __expf(nl)) + EPSF);
        }
    }
    __syncthreads();

    // ---- final combine (thread 0) ----
    if (tid == 0) {
        const float UPt = s_scw[0][3] + s_scw[1][3] + s_scw[2][3] + s_scw[3][3];
        float neg_loss = 0.f;
        #pragma unroll
        for (int n = 0; n < NNEG; ++n) neg_loss += s_nl[n];
        float pl = -s_s2t - UPt / SEt;                           // p_lambda
        float pos_loss = -__logf(1.f / (1.f + __expf(-pl)) + EPSF);
        out[b] = pos_loss - neg_loss;
    }
}

extern "C" void kernel_launch(void* const* d_in, const int* in_sizes, int n_in,
                              void* d_out, int out_size, void* d_ws, size_t ws_size,
                              hipStream_t stream) {
    const int*   s_nodes = (const int*)  d_in[0];
    const int*   t_nodes = (const int*)  d_in[1];
    const float* t_times = (const float*)d_in[2];
    const int*   h_nodes = (const int*)  d_in[3];
    const float* h_times = (const float*)d_in[4];
    const float* h_mask  = (const float*)d_in[5];
    const int*   n_nodes = (const int*)  d_in[6];
    const float* emb     = (const float*)d_in[7];
    const float* delta_w = (const float*)d_in[8];
    float*       out     = (float*)d_out;

    const int Bn = in_sizes[0];  // 4096
    htne_kernel<<<Bn, 256, 0, stream>>>(s_nodes, t_nodes, t_times, h_nodes,
                                        h_times, h_mask, n_nodes, emb, delta_w, out);
}

// Round 8
// 29.269 us; speedup vs baseline: 5.3115x; 1.0837x over previous
//
#include <hip/hip_runtime.h>
#include <math.h>

#define HH   50
#define NNEG 10
#define EE   128
#define EPSF 1e-6f

// One block per batch element. 16 groups of 16 lanes; each group owns one
// embedding row per iteration (lane holds 8 contiguous floats = 2x float4).
// Softmax max-subtraction is skipped (s2h <= 128*(2/128)^2 ~= 0.031, exp safe;
// validated absmax=0 in rounds 3-7), so row weights are formed in the SAME
// pass the row is loaded -> his rows gathered exactly once.
// Best-measured structure (round 4: 29.3 us). Rounds 5/6/7 tested fusion,
// 1-wave-per-element, and forced register prefetch: all neutral or worse ->
// kernel is memory-gather service-time bound, not latency/occupancy bound.
__global__ __launch_bounds__(256, 8) void htne_kernel(
    const int*   __restrict__ s_nodes,   // [B,1]
    const int*   __restrict__ t_nodes,   // [B,1]
    const float* __restrict__ t_times,   // [B,1]
    const int*   __restrict__ h_nodes,   // [B,H]
    const float* __restrict__ h_times,   // [B,H]
    const float* __restrict__ h_mask,    // [B,H]
    const int*   __restrict__ n_nodes,   // [B,N]
    const float* __restrict__ emb,       // [V,E]
    const float* __restrict__ delta_w,   // [V,1]
    float*       __restrict__ out)       // [B]
{
    __shared__ int   s_hidx[HH];
    __shared__ float s_ht[HH];
    __shared__ float s_hm[HH];
    __shared__ int   s_nidx[NNEG];
    __shared__ float s_part[4][EE];      // per-wave unnormalized hbar partials
    __shared__ float s_scw[4][4];        // per-wave SE, UW, UH, UP
    __shared__ float s_s2t;
    __shared__ float s_nl[NNEG];

    const int b    = blockIdx.x;
    const int tid  = threadIdx.x;
    const int wid  = tid >> 6;
    const int lane = tid & 63;
    const int g    = tid >> 4;           // 16-lane group id, 0..15
    const int sub  = tid & 15;           // lane-in-group

    // ---- preload per-batch metadata into LDS ----
    if (tid < HH) {
        s_hidx[tid] = h_nodes[b * HH + tid];
        s_ht[tid]   = h_times[b * HH + tid];
        s_hm[tid]   = h_mask[b * HH + tid];
    } else if (tid < HH + NNEG) {
        s_nidx[tid - HH] = n_nodes[b * NNEG + (tid - HH)];
    }

    const int   sidx  = s_nodes[b];
    const int   tidx  = t_nodes[b];
    const float tt    = t_times[b];
    const float delta = delta_w[sidx];

    // per-lane 8-elem slice of src/tar rows (broadcast across groups via cache)
    float sva[8], tva[8];
    {
        float4 a0 = *(const float4*)(emb + (size_t)sidx * EE + sub * 8);
        float4 a1 = *(const float4*)(emb + (size_t)sidx * EE + sub * 8 + 4);
        float4 b0 = *(const float4*)(emb + (size_t)tidx * EE + sub * 8);
        float4 b1 = *(const float4*)(emb + (size_t)tidx * EE + sub * 8 + 4);
        sva[0]=a0.x; sva[1]=a0.y; sva[2]=a0.z; sva[3]=a0.w;
        sva[4]=a1.x; sva[5]=a1.y; sva[6]=a1.z; sva[7]=a1.w;
        tva[0]=b0.x; tva[1]=b0.y; tva[2]=b0.z; tva[3]=b0.w;
        tva[4]=b1.x; tva[5]=b1.y; tva[6]=b1.z; tva[7]=b1.w;
    }

    __syncthreads();

    // ---- Stage A: 50 his rows + 1 (src-tar) task over 16 groups, single pass ----
    float SE = 0.f, UW = 0.f, UH = 0.f, UP = 0.f;
    float hb[8] = {0.f,0.f,0.f,0.f,0.f,0.f,0.f,0.f};

    #pragma unroll
    for (int it = 0; it < 4; ++it) {
        const int t = g + it * 16;
        if (t < HH) {
            const int idx = s_hidx[t];
            const float* hrow = emb + (size_t)idx * EE + sub * 8;
            float4 h0 = *(const float4*)(hrow);
            float4 h1 = *(const float4*)(hrow + 4);
            float hv[8] = {h0.x,h0.y,h0.z,h0.w,h1.x,h1.y,h1.z,h1.w};
            float a = 0.f, c = 0.f, q = 0.f;
            #pragma unroll
            for (int k = 0; k < 8; ++k) {
                float d1 = hv[k] - sva[k];
                float d2 = hv[k] - tva[k];
                a = fmaf(d1, d1, a);       // ||his-src||^2 partial
                c = fmaf(d2, d2, c);       // ||his-tar||^2 partial
                q = fmaf(hv[k], hv[k], q); // ||his||^2 partial
            }
            #pragma unroll
            for (int off = 1; off <= 8; off <<= 1) {
                a += __shfl_xor(a, off);
                c += __shfl_xor(c, off);
                q += __shfl_xor(q, off);
            }
            const float e1 = expf(-a);                       // softmax numerator
            const float dt = fabsf(tt - s_ht[t]);
            const float u  = e1 * expf(delta * dt) * s_hm[t]; // unnorm weight
            SE += e1; UW += u; UH += u * q; UP += u * c;
            #pragma unroll
            for (int k = 0; k < 8; ++k) hb[k] = fmaf(u, hv[k], hb[k]);
        } else if (t == HH) {  // group 2, it 3: ||src-tar||^2
            float a = 0.f;
            #pragma unroll
            for (int k = 0; k < 8; ++k) {
                float d = sva[k] - tva[k];
                a = fmaf(d, d, a);
            }
            #pragma unroll
            for (int off = 1; off <= 8; off <<= 1) a += __shfl_xor(a, off);
            if (sub == 0) s_s2t = a;
        }
    }

    // ---- cross-group butterfly (xor 16, 32) then per-wave LDS exchange ----
    #pragma unroll
    for (int off = 16; off <= 32; off <<= 1) {
        SE += __shfl_xor(SE, off);
        UW += __shfl_xor(UW, off);
        UH += __shfl_xor(UH, off);
        UP += __shfl_xor(UP, off);
        #pragma unroll
        for (int k = 0; k < 8; ++k) hb[k] += __shfl_xor(hb[k], off);
    }
    if (lane < 16) {
        *(float4*)(&s_part[wid][sub * 8])     = make_float4(hb[0],hb[1],hb[2],hb[3]);
        *(float4*)(&s_part[wid][sub * 8 + 4]) = make_float4(hb[4],hb[5],hb[6],hb[7]);
    }
    if (lane == 0) {
        s_scw[wid][0] = SE; s_scw[wid][1] = UW;
        s_scw[wid][2] = UH; s_scw[wid][3] = UP;
    }
    __syncthreads();

    const float SEt = s_scw[0][0] + s_scw[1][0] + s_scw[2][0] + s_scw[3][0];
    const float UWt = s_scw[0][1] + s_scw[1][1] + s_scw[2][1] + s_scw[3][1];
    const float UHt = s_scw[0][2] + s_scw[1][2] + s_scw[2][2] + s_scw[3][2];
    const float UPt = s_scw[0][3] + s_scw[1][3] + s_scw[2][3] + s_scw[3][3];

    // ---- Stage B: 10 neg rows, one per group, loaded once ----
    if (g < NNEG) {
        float hbs[8];
        #pragma unroll
        for (int k = 0; k < 8; ++k)
            hbs[k] = s_part[0][sub*8+k] + s_part[1][sub*8+k]
                   + s_part[2][sub*8+k] + s_part[3][sub*8+k];
        const int idx = s_nidx[g];
        const float* nrow = emb + (size_t)idx * EE + sub * 8;
        float4 n0 = *(const float4*)(nrow);
        float4 n1 = *(const float4*)(nrow + 4);
        float nv[8] = {n0.x,n0.y,n0.z,n0.w,n1.x,n1.y,n1.z,n1.w};
        float a = 0.f, q = 0.f, d = 0.f;
        #pragma unroll
        for (int k = 0; k < 8; ++k) {
            float d1 = nv[k] - sva[k];
            a = fmaf(d1, d1, a);           // ||src-neg||^2 partial
            q = fmaf(nv[k], nv[k], q);     // ||neg||^2 partial
            d = fmaf(hbs[k], nv[k], d);    // uhbar . neg partial
        }
        #pragma unroll
        for (int off = 1; off <= 8; off <<= 1) {
            a += __shfl_xor(a, off);
            q += __shfl_xor(q, off);
            d += __shfl_xor(d, off);
        }
        if (sub == 0) {
            float nl = -a - (UHt + q * UWt - 2.f * d) / SEt;   // n_lambda
            float sg = 1.f / (1.f + expf(nl));                 // sigmoid(-nl)
            s_nl[g] = logf(sg + EPSF);
        }
    }
    __syncthreads();

    // ---- Final combine ----
    if (tid == 0) {
        float neg_loss = 0.f;
        #pragma unroll
        for (int n = 0; n < NNEG; ++n) neg_loss += s_nl[n];
        float pl = -s_s2t - UPt / SEt;                         // p_lambda
        float sg = 1.f / (1.f + expf(-pl));
        float pos_loss = -logf(sg + EPSF);
        out[b] = pos_loss - neg_loss;
    }
}

extern "C" void kernel_launch(void* const* d_in, const int* in_sizes, int n_in,
                              void* d_out, int out_size, void* d_ws, size_t ws_size,
                              hipStream_t stream) {
    const int*   s_nodes = (const int*)  d_in[0];
    const int*   t_nodes = (const int*)  d_in[1];
    const float* t_times = (const float*)d_in[2];
    const int*   h_nodes = (const int*)  d_in[3];
    const float* h_times = (const float*)d_in[4];
    const float* h_mask  = (const float*)d_in[5];
    const int*   n_nodes = (const int*)  d_in[6];
    const float* emb     = (const float*)d_in[7];
    const float* delta_w = (const float*)d_in[8];
    float*       out     = (float*)d_out;

    const int Bn = in_sizes[0];  // 4096
    htne_kernel<<<Bn, 256, 0, stream>>>(s_nodes, t_nodes, t_times, h_nodes,
                                        h_times, h_mask, n_nodes, emb, delta_w, out);
}